// Round 1
// baseline (787.321 us; speedup 1.0000x reference)
//
#include <hip/hip_runtime.h>
#include <stdint.h>
#include <math.h>

#define NEGV -1000000000.0f

constexpr int NG   = 256;   // graphs
constexpr int NL   = 32;    // nodes per graph == L == steps
constexpr int ST   = 33;    // padded LDS stride
constexpr int NT   = 1024;  // threads per block
constexpr int NTOT = 8192;  // total nodes (output is NTOT x NTOT)

__device__ __forceinline__ float lrelu(float v) { return v > 0.f ? v : 0.01f * v; }

__device__ __forceinline__ uint32_t pack_bf2(float a, float b) {
  uint32_t ua = __float_as_uint(a); ua = (ua + 0x7fffu + ((ua >> 16) & 1u)) >> 16;
  uint32_t ub = __float_as_uint(b); ub = (ub + 0x7fffu + ((ub >> 16) & 1u)) >> 16;
  return ua | (ub << 16);
}
__device__ __forceinline__ float bflo(uint32_t w) { return __uint_as_float(w << 16); }
__device__ __forceinline__ float bfhi(uint32_t w) { return __uint_as_float(w & 0xffff0000u); }

__global__ __launch_bounds__(NT) void prims_fused(
    const float* __restrict__ x, const float* __restrict__ edge_attr,
    const float* __restrict__ W_enc, const float* __restrict__ W_m1,
    const float* __restrict__ W_m2, const float* __restrict__ W_u,
    const float* __restrict__ W_ih, const float* __restrict__ W_hh,
    const float* __restrict__ W_mst, const float* __restrict__ W_p1,
    const float* __restrict__ W_p2, float* __restrict__ out)
{
  __shared__ float sh[NL * ST];     // hidden state h
  __shared__ float senc[NL * ST];   // enc
  __shared__ float sA[NL * ST];     // dst-part of msg pre-act; reused as u; reused as C1
  __shared__ float sB[NL * ST];     // src-part of msg pre-act; reused as C2
  __shared__ float saggr[NL * ST];  // segment max
  __shared__ float sea[NL * ST];    // edge attr, sea[j*ST + i] = ea(src=i, dst=j)
  __shared__ float sprev[NL];
  __shared__ float sWenc[NL * ST];  // W_enc 32x33
  __shared__ float sW1d[NL * ST];   // W_m1[:, :32]
  __shared__ float sW1s[NL * ST];   // W_m1[:, 32:64]
  __shared__ float swea[NL];        // W_m1[:, 64]; reused for W_p1[:,64]
  __shared__ float sWu[NL * 65];    // W_u 32x64, stride 65
  __shared__ uint32_t sWih2[96 * 17]; // bf16x2-packed W_ih
  __shared__ uint32_t sWhh2[96 * 17]; // bf16x2-packed W_hh

  const int t = threadIdx.x;
  const int g = blockIdx.x;
  const int p = t >> 5;   // node index (or dst j / src i depending on phase)
  const int k = t & 31;   // feature index (or src i / dst j)

  // ---- one-time staging ----
  for (int idx = t; idx < NL * ST; idx += NT) sWenc[idx] = W_enc[idx]; // exact layout match
  for (int idx = t; idx < NL * 65; idx += NT) {
    int r = idx / 65, c = idx % 65;
    float v = W_m1[idx];
    if (c < 32)      sW1d[r * ST + c] = v;
    else if (c < 64) sW1s[r * ST + (c - 32)] = v;
    else             swea[r] = v;
  }
  for (int idx = t; idx < NL * 64; idx += NT) {
    int r = idx >> 6, c = idx & 63;
    sWu[r * 65 + c] = W_u[idx];
  }
  for (int idx = t; idx < 96 * 16; idx += NT) {
    int q = idx >> 4, c2 = idx & 15;
    sWih2[q * 17 + c2] = pack_bf2(W_ih[q * 32 + 2 * c2], W_ih[q * 32 + 2 * c2 + 1]);
    sWhh2[q * 17 + c2] = pack_bf2(W_hh[q * 32 + 2 * c2], W_hh[q * 32 + 2 * c2 + 1]);
  }
  {
    // edge e = i*32 + j (src i, dst j) -> sea[j*ST + i]
    int i = t >> 5, j = t & 31;
    sea[j * ST + i] = edge_attr[g * 1024 + t];
  }
  for (int idx = t; idx < NL * ST; idx += NT) sh[idx] = 0.f;
  if (t < NL) sprev[t] = x[(size_t)(g * NL + t) * 32];  // x[:, 0]
  __syncthreads();

  // ---- 32 message-passing steps ----
  for (int s = 0; s < 32; ++s) {
    // NEG-fill slice of this graph's 32-row band (overlaps with compute)
    #pragma unroll
    for (int q = 0; q < 2; ++q) {
      int idx = (s * 2 + q) * NT + t;       // 0 .. 65535
      int row = idx >> 11;                  // / 2048 float4s per row
      int c4  = idx & 2047;
      float4* dptr = reinterpret_cast<float4*>(out + (size_t)(g * NL + row) * NTOT) + c4;
      *dptr = make_float4(NEGV, NEGV, NEGV, NEGV);
    }

    // enc = relu([prev | h] @ W_enc.T)
    {
      float acc = sWenc[k * ST] * sprev[p];
      #pragma unroll
      for (int c = 0; c < 32; ++c) acc = fmaf(sWenc[k * ST + 1 + c], sh[p * ST + c], acc);
      senc[p * ST + k] = fmaxf(acc, 0.f);
    }
    __syncthreads();

    // A = enc @ W_m1[:, :32].T   B = enc @ W_m1[:, 32:64].T
    {
      float a = 0.f, b = 0.f;
      #pragma unroll
      for (int c = 0; c < 32; ++c) {
        float e = senc[p * ST + c];
        a = fmaf(sW1d[k * ST + c], e, a);
        b = fmaf(sW1s[k * ST + c], e, b);
      }
      sA[p * ST + k] = a;
      sB[p * ST + k] = b;
    }
    __syncthreads();

    // edge phase: thread = edge (dst j = p, src i = k)
    {
      const int j = p, i = k;
      float eat = sea[j * ST + i];
      float P[32];
      #pragma unroll
      for (int c = 0; c < 32; ++c)
        P[c] = lrelu(sA[j * ST + c] + sB[i * ST + c] + eat * swea[c]);
      #pragma unroll 4
      for (int kk = 0; kk < 32; ++kk) {
        float acc = 0.f;
        #pragma unroll
        for (int c = 0; c < 32; ++c) acc = fmaf(W_m2[kk * 32 + c], P[c], acc);  // uniform -> s_load
        float mk = lrelu(acc);
        mk = fmaxf(mk, __shfl_xor(mk, 1));
        mk = fmaxf(mk, __shfl_xor(mk, 2));
        mk = fmaxf(mk, __shfl_xor(mk, 4));
        mk = fmaxf(mk, __shfl_xor(mk, 8));
        mk = fmaxf(mk, __shfl_xor(mk, 16));
        if (i == 0) saggr[j * ST + kk] = mk;   // max over src i for dst j
      }
    }
    __syncthreads();

    // u = lrelu([enc | aggr] @ W_u.T)   (stored into sA)
    {
      float acc = 0.f;
      #pragma unroll
      for (int c = 0; c < 32; ++c) {
        acc = fmaf(sWu[k * 65 + c],      senc[p * ST + c],  acc);
        acc = fmaf(sWu[k * 65 + 32 + c], saggr[p * ST + c], acc);
      }
      sA[p * ST + k] = lrelu(acc);
    }
    __syncthreads();

    // GRU
    float hnew;
    {
      float gir = 0.f, giz = 0.f, gin = 0.f, ghr = 0.f, ghz = 0.f, ghn = 0.f;
      #pragma unroll
      for (int c2 = 0; c2 < 16; ++c2) {
        float u0 = sA[p * ST + 2 * c2], u1 = sA[p * ST + 2 * c2 + 1];
        float h0 = sh[p * ST + 2 * c2], h1 = sh[p * ST + 2 * c2 + 1];
        uint32_t wir = sWih2[k * 17 + c2];
        uint32_t wiz = sWih2[(32 + k) * 17 + c2];
        uint32_t win = sWih2[(64 + k) * 17 + c2];
        uint32_t whr = sWhh2[k * 17 + c2];
        uint32_t whz = sWhh2[(32 + k) * 17 + c2];
        uint32_t whn = sWhh2[(64 + k) * 17 + c2];
        gir = fmaf(bflo(wir), u0, gir); gir = fmaf(bfhi(wir), u1, gir);
        giz = fmaf(bflo(wiz), u0, giz); giz = fmaf(bfhi(wiz), u1, giz);
        gin = fmaf(bflo(win), u0, gin); gin = fmaf(bfhi(win), u1, gin);
        ghr = fmaf(bflo(whr), h0, ghr); ghr = fmaf(bfhi(whr), h1, ghr);
        ghz = fmaf(bflo(whz), h0, ghz); ghz = fmaf(bfhi(whz), h1, ghz);
        ghn = fmaf(bflo(whn), h0, ghn); ghn = fmaf(bfhi(whn), h1, ghn);
      }
      float r  = 1.f / (1.f + expf(-(gir + ghr)));
      float z  = 1.f / (1.f + expf(-(giz + ghz)));
      float nn = tanhf(gin + r * ghn);
      hnew = (1.f - z) * nn + z * sh[p * ST + k];
    }
    __syncthreads();
    sh[p * ST + k] = hnew;
    __syncthreads();

    // mst score + masked argmax + prev update (one half-wave)
    if (t < 32) {
      float acc = 0.f;
      #pragma unroll
      for (int c = 0; c < 32; ++c) {
        acc = fmaf(W_mst[c],      senc[t * ST + c], acc);   // uniform -> s_load
        acc = fmaf(W_mst[32 + c], sh[t * ST + c],   acc);
      }
      float val = (sprev[t] > 0.f) ? NEGV : acc;
      int idx = t;
      #pragma unroll
      for (int mask = 16; mask >= 1; mask >>= 1) {
        float ov = __shfl_xor(val, mask);
        int   oi = __shfl_xor(idx, mask);
        if (ov > val || (ov == val && oi < idx)) { val = ov; idx = oi; }
      }
      if (t == idx) sprev[t] = 1.0f;   // first index of max (ties -> smallest idx)
    }
    __syncthreads();
  }

  // ---- final predictor ----
  // C1 = h @ W_p1[:, :32].T (src part) -> sA ; C2 = h @ W_p1[:, 32:64].T (dst part) -> sB
  {
    float c1 = 0.f, c2 = 0.f;
    #pragma unroll
    for (int c = 0; c < 32; ++c) {
      float hc = sh[p * ST + c];
      c1 = fmaf(W_p1[k * 65 + c],      hc, c1);
      c2 = fmaf(W_p1[k * 65 + 32 + c], hc, c2);
    }
    sA[p * ST + k] = c1;
    sB[p * ST + k] = c2;
  }
  if (t < 32) swea[t] = W_p1[t * 65 + 64];
  __syncthreads();

  // out(src=i, dst=j) ; thread: i = t>>5, j = t&31
  {
    const int i = p, j = k;
    float eat = sea[j * ST + i];
    float acc = 0.f;
    #pragma unroll
    for (int c = 0; c < 32; ++c) {
      float v = sA[i * ST + c] + sB[j * ST + c] + eat * swea[c];
      acc = fmaf(W_p2[c], fmaxf(v, 0.f), acc);   // uniform -> s_load
    }
    out[(size_t)(g * NL + i) * NTOT + (g * NL + j)] = acc;
  }
}

extern "C" void kernel_launch(void* const* d_in, const int* in_sizes, int n_in,
                              void* d_out, int out_size, void* d_ws, size_t ws_size,
                              hipStream_t stream) {
  const float* x         = (const float*)d_in[0];
  const float* edge_attr = (const float*)d_in[1];
  const float* W_enc     = (const float*)d_in[2];
  const float* W_m1      = (const float*)d_in[3];
  const float* W_m2      = (const float*)d_in[4];
  const float* W_u       = (const float*)d_in[5];
  const float* W_ih      = (const float*)d_in[6];
  const float* W_hh      = (const float*)d_in[7];
  const float* W_mst     = (const float*)d_in[8];
  const float* W_p1      = (const float*)d_in[9];
  const float* W_p2      = (const float*)d_in[10];
  float* out = (float*)d_out;

  hipLaunchKernelGGL(prims_fused, dim3(NG), dim3(NT), 0, stream,
                     x, edge_attr, W_enc, W_m1, W_m2, W_u, W_ih, W_hh,
                     W_mst, W_p1, W_p2, out);
}

// Round 3
// 345.169 us; speedup vs baseline: 2.2810x; 2.2810x over previous
//
#include <hip/hip_runtime.h>
#include <stdint.h>
#include <math.h>

#define NEGV -1000000000.0f

constexpr int NG   = 256;   // graphs
constexpr int NL   = 32;    // nodes per graph == L == steps
constexpr int ST   = 33;    // padded LDS stride
constexpr int NT   = 1024;  // threads per block
constexpr int NTOT = 8192;  // total nodes (output is NTOT x NTOT)

typedef __attribute__((ext_vector_type(8))) short bf16x8;   // 8 bf16 in 4 VGPRs
typedef __attribute__((ext_vector_type(4))) float f32x4;

__device__ __forceinline__ float lrelu(float v) { return v > 0.f ? v : 0.01f * v; }

__device__ __forceinline__ uint32_t pack_bf2_rne(float a, float b) {
  uint32_t ua = __float_as_uint(a); ua = (ua + 0x7fffu + ((ua >> 16) & 1u)) >> 16;
  uint32_t ub = __float_as_uint(b); ub = (ub + 0x7fffu + ((ub >> 16) & 1u)) >> 16;
  return ua | (ub << 16);
}
__device__ __forceinline__ float bflo(uint32_t w) { return __uint_as_float(w << 16); }
__device__ __forceinline__ float bfhi(uint32_t w) { return __uint_as_float(w & 0xffff0000u); }

__device__ __forceinline__ void wave_fence() {
  asm volatile("s_waitcnt lgkmcnt(0)" ::: "memory");
  __builtin_amdgcn_sched_barrier(0);
}
__device__ __forceinline__ void lds_barrier() {
  asm volatile("s_waitcnt lgkmcnt(0)" ::: "memory");
  __builtin_amdgcn_sched_barrier(0);
  __builtin_amdgcn_s_barrier();
}

__device__ __forceinline__ float fsigmoid(float x) {
  return __builtin_amdgcn_rcpf(1.f + __expf(-x));
}
__device__ __forceinline__ float ftanh(float x) {
  x = fminf(fmaxf(x, -15.f), 15.f);
  float e = __expf(2.f * x);
  return (e - 1.f) * __builtin_amdgcn_rcpf(e + 1.f);
}

__global__ __launch_bounds__(NT, 4) void prims_fused(
    const float* __restrict__ x, const float* __restrict__ edge_attr,
    const float* __restrict__ W_enc, const float* __restrict__ W_m1,
    const float* __restrict__ W_m2, const float* __restrict__ W_u,
    const float* __restrict__ W_ih, const float* __restrict__ W_hh,
    const float* __restrict__ W_mst, const float* __restrict__ W_p1,
    const float* __restrict__ W_p2, float* __restrict__ out)
{
  __shared__ float sh[NL * ST];     // hidden state h
  __shared__ float senc[NL * ST];   // enc
  __shared__ float sA[NL * ST];     // dst-part of msg pre-act; reused as u; reused as C1
  __shared__ float sB[NL * ST];     // src-part of msg pre-act; reused as C2
  __shared__ float saggr[NL * ST];  // segment max
  __shared__ float sea[NL * ST];    // sea[j*ST + i] = ea(src=i, dst=j)
  __shared__ float sprev[NL];
  __shared__ float smst[NL];
  __shared__ float sWenc[NL * ST];  // W_enc 32x33
  __shared__ float sW1d[NL * ST];   // W_m1[:, :32]
  __shared__ float sW1s[NL * ST];   // W_m1[:, 32:64]
  __shared__ float swea[NL];        // W_m1[:, 64]; later W_p1[:,64]
  __shared__ float sWmst[2 * NL];
  __shared__ float sWu[NL * 65];    // W_u 32x64, stride 65
  __shared__ uint32_t sWih2[96 * 17]; // bf16x2-packed W_ih
  __shared__ uint32_t sWhh2[96 * 17]; // bf16x2-packed W_hh

  const int t    = threadIdx.x;
  const int g    = blockIdx.x;
  const int p    = t >> 5;   // node index
  const int k    = t & 31;   // feature index
  const int w    = t >> 6;   // wave id (16 waves)
  const int lane = t & 63;
  const int m16  = lane & 15;          // MFMA row/col within tile
  const int c0   = (lane >> 4) * 8;    // MFMA k-chunk base

  // ---- W_m2^T B-fragments (resident in registers for whole kernel) ----
  bf16x8 bf0, bf1;
  {
    union { uint32_t u[4]; bf16x8 v; } p0, p1;
    #pragma unroll
    for (int q = 0; q < 4; ++q) {
      p0.u[q] = pack_bf2_rne(W_m2[m16 * 32 + c0 + 2 * q], W_m2[m16 * 32 + c0 + 2 * q + 1]);
      p1.u[q] = pack_bf2_rne(W_m2[(16 + m16) * 32 + c0 + 2 * q], W_m2[(16 + m16) * 32 + c0 + 2 * q + 1]);
    }
    bf0 = p0.v; bf1 = p1.v;
  }

  // ---- one-time staging ----
  for (int idx = t; idx < NL * ST; idx += NT) sWenc[idx] = W_enc[idx];
  for (int idx = t; idx < NL * 65; idx += NT) {
    int r = idx / 65, c = idx % 65;
    float v = W_m1[idx];
    if (c < 32)      sW1d[r * ST + c] = v;
    else if (c < 64) sW1s[r * ST + (c - 32)] = v;
    else             swea[r] = v;
  }
  for (int idx = t; idx < NL * 64; idx += NT) {
    int r = idx >> 6, c = idx & 63;
    sWu[r * 65 + c] = W_u[idx];
  }
  for (int idx = t; idx < 96 * 16; idx += NT) {
    int q = idx >> 4, c2 = idx & 15;
    sWih2[q * 17 + c2] = pack_bf2_rne(W_ih[q * 32 + 2 * c2], W_ih[q * 32 + 2 * c2 + 1]);
    sWhh2[q * 17 + c2] = pack_bf2_rne(W_hh[q * 32 + 2 * c2], W_hh[q * 32 + 2 * c2 + 1]);
  }
  if (t < 2 * NL) sWmst[t] = W_mst[t];
  {
    int i = t >> 5, j = t & 31;              // edge t = i*32 + j (src i, dst j)
    sea[j * ST + i] = edge_attr[g * 1024 + t];
  }
  for (int idx = t; idx < NL * ST; idx += NT) sh[idx] = 0.f;
  if (t < NL) sprev[t] = x[(size_t)(g * NL + t) * 32];  // x[:, 0]
  __syncthreads();

  // ---- 32 message-passing steps ----
  for (int s = 0; s < 32; ++s) {
    // NEG-fill slice of this graph's 32-row band (skips diagonal block; overlaps compute)
    {
      const f32x4 nv = {NEGV, NEGV, NEGV, NEGV};
      #pragma unroll
      for (int q = 0; q < 2; ++q) {
        int idx = (s * 2 + q) * NT + t;     // 0 .. 65535
        int row = idx >> 11;                // 2048 float4 per row
        int c4  = idx & 2047;
        if ((c4 >> 3) != g) {
          f32x4* dptr = reinterpret_cast<f32x4*>(out + (size_t)(g * NL + row) * NTOT) + c4;
          __builtin_nontemporal_store(nv, dptr);
        }
      }
    }

    // enc = relu([prev | h] @ W_enc.T)   (own node rows)
    {
      const float pv = sprev[p];
      const float* shp = &sh[p * ST];
      const float* we  = &sWenc[k * ST];
      float acc = we[0] * pv;
      #pragma unroll
      for (int c = 0; c < 32; ++c) acc = fmaf(we[1 + c], shp[c], acc);
      senc[p * ST + k] = fmaxf(acc, 0.f);
    }
    wave_fence();

    // A = enc @ W_m1[:, :32].T   B = enc @ W_m1[:, 32:64].T   (own rows)
    {
      const float* ep = &senc[p * ST];
      float a = 0.f, b = 0.f;
      #pragma unroll
      for (int c = 0; c < 32; ++c) {
        float e = ep[c];
        a = fmaf(sW1d[k * ST + c], e, a);
        b = fmaf(sW1s[k * ST + c], e, b);
      }
      sA[p * ST + k] = a;
      sB[p * ST + k] = b;
    }
    lds_barrier();   // B1: sA/sB of all nodes visible

    // edge phase via MFMA: wave w owns dst j = 2w, 2w+1 (64 edges)
    {
      float wv[8];
      #pragma unroll
      for (int e = 0; e < 8; ++e) wv[e] = swea[c0 + e];
      const f32x4 zero = {0.f, 0.f, 0.f, 0.f};
      #pragma unroll
      for (int jg = 0; jg < 2; ++jg) {
        const int j = 2 * w + jg;
        float Aj[8];
        #pragma unroll
        for (int e = 0; e < 8; ++e) Aj[e] = sA[j * ST + c0 + e];
        const float ea0 = sea[j * ST + m16];
        const float ea1 = sea[j * ST + 16 + m16];
        const float* b0 = &sB[m16 * ST + c0];
        const float* b1 = &sB[(16 + m16) * ST + c0];
        union { uint32_t u[4]; bf16x8 v; } a0, a1;
        #pragma unroll
        for (int q = 0; q < 4; ++q) {
          float v00 = lrelu(Aj[2*q]   + fmaf(ea0, wv[2*q],   b0[2*q]));
          float v01 = lrelu(Aj[2*q+1] + fmaf(ea0, wv[2*q+1], b0[2*q+1]));
          float v10 = lrelu(Aj[2*q]   + fmaf(ea1, wv[2*q],   b1[2*q]));
          float v11 = lrelu(Aj[2*q+1] + fmaf(ea1, wv[2*q+1], b1[2*q+1]));
          a0.u[q] = (__float_as_uint(v00) >> 16) | (__float_as_uint(v01) & 0xffff0000u);
          a1.u[q] = (__float_as_uint(v10) >> 16) | (__float_as_uint(v11) & 0xffff0000u);
        }
        f32x4 d00 = __builtin_amdgcn_mfma_f32_16x16x32_bf16(a0.v, bf0, zero, 0, 0, 0);
        f32x4 d01 = __builtin_amdgcn_mfma_f32_16x16x32_bf16(a0.v, bf1, zero, 0, 0, 0);
        f32x4 d10 = __builtin_amdgcn_mfma_f32_16x16x32_bf16(a1.v, bf0, zero, 0, 0, 0);
        f32x4 d11 = __builtin_amdgcn_mfma_f32_16x16x32_bf16(a1.v, bf1, zero, 0, 0, 0);
        #pragma unroll
        for (int nt = 0; nt < 2; ++nt) {
          f32x4 da = nt ? d01 : d00;
          f32x4 db = nt ? d11 : d10;
          float mv = -3.4e38f;
          #pragma unroll
          for (int r = 0; r < 4; ++r) {
            mv = fmaxf(mv, lrelu(da[r]));
            mv = fmaxf(mv, lrelu(db[r]));
          }
          mv = fmaxf(mv, __shfl_xor(mv, 16));
          mv = fmaxf(mv, __shfl_xor(mv, 32));
          if (lane < 16) saggr[j * ST + nt * 16 + lane] = mv;  // max over src i
        }
      }
    }
    wave_fence();

    // u = lrelu([enc | aggr] @ W_u.T)  -> sA (own rows; other waves only read own sA rows)
    {
      const float* ep = &senc[p * ST];
      const float* ap = &saggr[p * ST];
      float acc = 0.f;
      #pragma unroll
      for (int c = 0; c < 32; ++c) {
        acc = fmaf(sWu[k * 65 + c],      ep[c], acc);
        acc = fmaf(sWu[k * 65 + 32 + c], ap[c], acc);
      }
      sA[p * ST + k] = lrelu(acc);
    }
    wave_fence();

    // GRU (own rows)
    float hnew;
    {
      float gir = 0.f, giz = 0.f, gin = 0.f, ghr = 0.f, ghz = 0.f, ghn = 0.f;
      #pragma unroll
      for (int c2 = 0; c2 < 16; ++c2) {
        float u0 = sA[p * ST + 2 * c2], u1 = sA[p * ST + 2 * c2 + 1];
        float h0 = sh[p * ST + 2 * c2], h1 = sh[p * ST + 2 * c2 + 1];
        uint32_t wir = sWih2[k * 17 + c2];
        uint32_t wiz = sWih2[(32 + k) * 17 + c2];
        uint32_t win = sWih2[(64 + k) * 17 + c2];
        uint32_t whr = sWhh2[k * 17 + c2];
        uint32_t whz = sWhh2[(32 + k) * 17 + c2];
        uint32_t whn = sWhh2[(64 + k) * 17 + c2];
        gir = fmaf(bflo(wir), u0, gir); gir = fmaf(bfhi(wir), u1, gir);
        giz = fmaf(bflo(wiz), u0, giz); giz = fmaf(bfhi(wiz), u1, giz);
        gin = fmaf(bflo(win), u0, gin); gin = fmaf(bfhi(win), u1, gin);
        ghr = fmaf(bflo(whr), h0, ghr); ghr = fmaf(bfhi(whr), h1, ghr);
        ghz = fmaf(bflo(whz), h0, ghz); ghz = fmaf(bfhi(whz), h1, ghz);
        ghn = fmaf(bflo(whn), h0, ghn); ghn = fmaf(bfhi(whn), h1, ghn);
      }
      float r  = fsigmoid(gir + ghr);
      float z  = fsigmoid(giz + ghz);
      float nn = ftanh(gin + r * ghn);
      hnew = (1.f - z) * nn + z * sh[p * ST + k];
    }
    wave_fence();              // all h reads done
    sh[p * ST + k] = hnew;
    wave_fence();              // h write visible to own wave

    // mst partial: all threads; reduce over feature lanes
    {
      float part = sWmst[k] * senc[p * ST + k] + sWmst[32 + k] * sh[p * ST + k];
      #pragma unroll
      for (int mask = 1; mask <= 16; mask <<= 1) part += __shfl_xor(part, mask);
      if (k == 0) smst[p] = part;
    }
    lds_barrier();   // B2: smst visible

    // masked argmax + prev update (one half-wave)
    if (t < 32) {
      float val = (sprev[t] > 0.f) ? NEGV : smst[t];
      int idx = t;
      #pragma unroll
      for (int mask = 16; mask >= 1; mask >>= 1) {
        float ov = __shfl_xor(val, mask);
        int   oi = __shfl_xor(idx, mask);
        if (ov > val || (ov == val && oi < idx)) { val = ov; idx = oi; }
      }
      if (t == idx) sprev[t] = 1.0f;   // first index of max
    }
    lds_barrier();   // B3: sprev visible
  }

  // ---- final predictor ----
  // C1 = h @ W_p1[:, :32].T (src part) -> sA ; C2 = h @ W_p1[:, 32:64].T (dst part) -> sB
  {
    float c1 = 0.f, c2 = 0.f;
    #pragma unroll
    for (int c = 0; c < 32; ++c) {
      float hc = sh[p * ST + c];
      c1 = fmaf(W_p1[k * 65 + c],      hc, c1);
      c2 = fmaf(W_p1[k * 65 + 32 + c], hc, c2);
    }
    sA[p * ST + k] = c1;
    sB[p * ST + k] = c2;
  }
  if (t < 32) swea[t] = W_p1[t * 65 + 64];
  lds_barrier();

  // out(src=i, dst=j) ; thread: i = t>>5, j = t&31
  {
    const int i = p, j = k;
    float eat = sea[j * ST + i];
    float acc = 0.f;
    #pragma unroll
    for (int c = 0; c < 32; ++c) {
      float v = sA[i * ST + c] + sB[j * ST + c] + eat * swea[c];
      acc = fmaf(W_p2[c], fmaxf(v, 0.f), acc);
    }
    out[(size_t)(g * NL + i) * NTOT + (g * NL + j)] = acc;
  }
}

extern "C" void kernel_launch(void* const* d_in, const int* in_sizes, int n_in,
                              void* d_out, int out_size, void* d_ws, size_t ws_size,
                              hipStream_t stream) {
  const float* x         = (const float*)d_in[0];
  const float* edge_attr = (const float*)d_in[1];
  const float* W_enc     = (const float*)d_in[2];
  const float* W_m1      = (const float*)d_in[3];
  const float* W_m2      = (const float*)d_in[4];
  const float* W_u       = (const float*)d_in[5];
  const float* W_ih      = (const float*)d_in[6];
  const float* W_hh      = (const float*)d_in[7];
  const float* W_mst     = (const float*)d_in[8];
  const float* W_p1      = (const float*)d_in[9];
  const float* W_p2      = (const float*)d_in[10];
  float* out = (float*)d_out;

  hipLaunchKernelGGL(prims_fused, dim3(NG), dim3(NT), 0, stream,
                     x, edge_attr, W_enc, W_m1, W_m2, W_u, W_ih, W_hh,
                     W_mst, W_p1, W_p2, out);
}

// Round 4
// 328.360 us; speedup vs baseline: 2.3977x; 1.0512x over previous
//
#include <hip/hip_runtime.h>
#include <stdint.h>
#include <math.h>

#define NEGV -1000000000.0f

constexpr int NG   = 256;   // graphs
constexpr int NL   = 32;    // nodes per graph == L == steps
constexpr int NT   = 1024;  // threads per block
constexpr int NTOT = 8192;  // total nodes
constexpr int S3   = 33;    // stride for per-lane-row-read arrays
constexpr int S4   = 34;    // stride for broadcast-read arrays (float2-aligned)

typedef __attribute__((ext_vector_type(8))) short bf16x8;
typedef __attribute__((ext_vector_type(4))) float f32x4;
typedef __attribute__((ext_vector_type(2))) float f32x2;

__device__ __forceinline__ float lrelu(float v) { return fmaxf(v, 0.01f * v); }

__device__ __forceinline__ uint32_t pack_bf2_rne(float a, float b) {
  uint32_t ua = __float_as_uint(a); ua = (ua + 0x7fffu + ((ua >> 16) & 1u)) >> 16;
  uint32_t ub = __float_as_uint(b); ub = (ub + 0x7fffu + ((ub >> 16) & 1u)) >> 16;
  return ua | (ub << 16);
}
// pack truncated-bf16 of lo,hi into one u32: low16 = lo>>16, high16 = hi&ffff0000
__device__ __forceinline__ uint32_t pack_tr(float lo, float hi) {
  return __builtin_amdgcn_perm(__float_as_uint(hi), __float_as_uint(lo), 0x07060302u);
}
// bf16x2 word -> float2
__device__ __forceinline__ f32x2 bf2f2(uint32_t w) {
  f32x2 r; r.x = __uint_as_float(w << 16); r.y = __uint_as_float(w & 0xffff0000u); return r;
}

__device__ __forceinline__ void lds_barrier() {
  asm volatile("s_waitcnt lgkmcnt(0)" ::: "memory");
  __builtin_amdgcn_sched_barrier(0);
  __builtin_amdgcn_s_barrier();
  __builtin_amdgcn_sched_barrier(0);
}

__device__ __forceinline__ float fsigmoid(float x) {
  return __builtin_amdgcn_rcpf(1.f + __expf(-x));
}
__device__ __forceinline__ float ftanh(float x) {
  x = fminf(fmaxf(x, -15.f), 15.f);
  float e = __expf(2.f * x);
  return (e - 1.f) * __builtin_amdgcn_rcpf(e + 1.f);
}

__global__ __launch_bounds__(NT, 4) void prims_fused(
    const float* __restrict__ x, const float* __restrict__ edge_attr,
    const float* __restrict__ W_enc, const float* __restrict__ W_m1,
    const float* __restrict__ W_m2, const float* __restrict__ W_u,
    const float* __restrict__ W_ih, const float* __restrict__ W_hh,
    const float* __restrict__ W_mst, const float* __restrict__ W_p1,
    const float* __restrict__ W_p2, float* __restrict__ out)
{
  __shared__ __align__(16) float sh[NL * S4];     // hidden state h
  __shared__ __align__(16) float senc[NL * S4];   // enc
  __shared__ __align__(16) float sA[NL * S4];     // msg dst-part; then u; then C1
  __shared__ __align__(16) float saggr[NL * S4];  // segment max
  __shared__ float sB[NL * S3];                   // msg src-part; then C2
  __shared__ float sea[NL * S3];                  // sea[j*S3 + i] = ea(src i, dst j)
  __shared__ __align__(8) float swea[NL];         // W_m1[:,64]; later W_p1[:,64]
  __shared__ float sprev[NL];
  __shared__ float smst[NL];
  __shared__ float swenc0[NL];
  __shared__ float sWmst[2 * NL];
  __shared__ f32x2 sWenc2[NL * 17];   // W_enc[:,1:33] pairs
  __shared__ f32x2 sW1d2[NL * 17];    // W_m1[:, 0:32] pairs
  __shared__ f32x2 sW1s2[NL * 17];    // W_m1[:,32:64] pairs
  __shared__ f32x2 sWu2[NL * 33];     // W_u pairs (64 cols = 32 pairs, pad 1)
  __shared__ uint32_t sWih2[96 * 17]; // bf16x2-packed W_ih
  __shared__ uint32_t sWhh2[96 * 17]; // bf16x2-packed W_hh

  const int t    = threadIdx.x;
  const int g    = blockIdx.x;
  const int p    = t >> 5;   // node row
  const int k    = t & 31;   // feature col
  const int w    = t >> 6;   // wave id (16)
  const int lane = t & 63;
  const int l32  = lane & 31;
  const int m16  = lane & 15;
  const int c0   = (lane >> 4) * 8;  // MFMA k-chunk base

  // ---- W_m2^T B-fragments, resident in registers ----
  bf16x8 bf0, bf1;
  {
    union { uint32_t u[4]; bf16x8 v; } p0, p1;
    #pragma unroll
    for (int q = 0; q < 4; ++q) {
      p0.u[q] = pack_bf2_rne(W_m2[m16 * 32 + c0 + 2 * q], W_m2[m16 * 32 + c0 + 2 * q + 1]);
      p1.u[q] = pack_bf2_rne(W_m2[(16 + m16) * 32 + c0 + 2 * q], W_m2[(16 + m16) * 32 + c0 + 2 * q + 1]);
    }
    bf0 = p0.v; bf1 = p1.v;
  }

  // ---- one-time staging ----
  for (int idx = t; idx < NL * 16; idx += NT) {
    int r = idx >> 4, c2 = idx & 15;
    sWenc2[r * 17 + c2] = (f32x2){W_enc[r * 33 + 1 + 2 * c2], W_enc[r * 33 + 2 + 2 * c2]};
    sW1d2[r * 17 + c2] = (f32x2){W_m1[r * 65 + 2 * c2],      W_m1[r * 65 + 2 * c2 + 1]};
    sW1s2[r * 17 + c2] = (f32x2){W_m1[r * 65 + 32 + 2 * c2], W_m1[r * 65 + 33 + 2 * c2]};
  }
  for (int idx = t; idx < NL * 32; idx += NT) {
    int r = idx >> 5, c2 = idx & 31;
    sWu2[r * 33 + c2] = (f32x2){W_u[r * 64 + 2 * c2], W_u[r * 64 + 2 * c2 + 1]};
  }
  for (int idx = t; idx < 96 * 16; idx += NT) {
    int q = idx >> 4, c2 = idx & 15;
    sWih2[q * 17 + c2] = pack_bf2_rne(W_ih[q * 32 + 2 * c2], W_ih[q * 32 + 2 * c2 + 1]);
    sWhh2[q * 17 + c2] = pack_bf2_rne(W_hh[q * 32 + 2 * c2], W_hh[q * 32 + 2 * c2 + 1]);
  }
  if (t < NL) { swenc0[t] = W_enc[t * 33]; swea[t] = W_m1[t * 65 + 64]; }
  if (t < 2 * NL) sWmst[t] = W_mst[t];
  {
    int i = t >> 5, j = t & 31;            // edge t = i*32+j
    sea[j * S3 + i] = edge_attr[g * 1024 + t];
  }
  for (int idx = t; idx < NL * S4; idx += NT) sh[idx] = 0.f;
  if (t < NL) sprev[t] = x[(size_t)(g * NL + t) * 32];
  __syncthreads();

  // ---- 32 steps ----
  for (int s = 0; s < 32; ++s) {
    // NEG-fill slice of this graph's band (skips diagonal block; overlaps compute)
    {
      const f32x4 nv = {NEGV, NEGV, NEGV, NEGV};
      #pragma unroll
      for (int q = 0; q < 2; ++q) {
        int idx = (s * 2 + q) * NT + t;
        int row = idx >> 11;
        int c4  = idx & 2047;
        if ((c4 >> 3) != g) {
          f32x4* dptr = reinterpret_cast<f32x4*>(out + (size_t)(g * NL + row) * NTOT) + c4;
          __builtin_nontemporal_store(nv, dptr);
        }
      }
    }

    // enc = relu([prev | h] @ W_enc.T)   (own rows)
    {
      const f32x2* h2 = (const f32x2*)&sh[p * S4];
      f32x2 acc2 = {0.f, 0.f};
      #pragma unroll
      for (int c2 = 0; c2 < 16; ++c2)
        acc2 = __builtin_elementwise_fma(sWenc2[k * 17 + c2], h2[c2], acc2);
      float acc = fmaf(swenc0[k], sprev[p], acc2.x + acc2.y);
      senc[p * S4 + k] = fmaxf(acc, 0.f);
    }

    // A/B = enc @ W_m1 halves  (own rows)
    {
      const f32x2* e2 = (const f32x2*)&senc[p * S4];
      f32x2 a2 = {0.f, 0.f}, b2 = {0.f, 0.f};
      #pragma unroll
      for (int c2 = 0; c2 < 16; ++c2) {
        f32x2 ev = e2[c2];
        a2 = __builtin_elementwise_fma(sW1d2[k * 17 + c2], ev, a2);
        b2 = __builtin_elementwise_fma(sW1s2[k * 17 + c2], ev, b2);
      }
      sA[p * S4 + k] = a2.x + a2.y;
      sB[p * S3 + k] = b2.x + b2.y;
    }
    lds_barrier();   // B1: sA/sB all rows visible

    // edge phase via MFMA: wave w owns dst j = 2w, 2w+1
    {
      const f32x2* wv2 = (const f32x2*)&swea[c0];
      float wv[8];
      #pragma unroll
      for (int q = 0; q < 4; ++q) { f32x2 v = wv2[q]; wv[2*q] = v.x; wv[2*q+1] = v.y; }
      const f32x4 zero = {0.f, 0.f, 0.f, 0.f};
      #pragma unroll
      for (int jg = 0; jg < 2; ++jg) {
        const int j = 2 * w + jg;
        const f32x2* aj2 = (const f32x2*)&sA[j * S4 + c0];
        float Aj[8];
        #pragma unroll
        for (int q = 0; q < 4; ++q) { f32x2 v = aj2[q]; Aj[2*q] = v.x; Aj[2*q+1] = v.y; }
        const float ea0 = sea[j * S3 + m16];
        const float ea1 = sea[j * S3 + 16 + m16];
        const float* b0 = &sB[m16 * S3 + c0];
        const float* b1 = &sB[(16 + m16) * S3 + c0];
        union { uint32_t u[4]; bf16x8 v; } a0, a1;
        #pragma unroll
        for (int q = 0; q < 4; ++q) {
          float v00 = lrelu(Aj[2*q]   + fmaf(ea0, wv[2*q],   b0[2*q]));
          float v01 = lrelu(Aj[2*q+1] + fmaf(ea0, wv[2*q+1], b0[2*q+1]));
          float v10 = lrelu(Aj[2*q]   + fmaf(ea1, wv[2*q],   b1[2*q]));
          float v11 = lrelu(Aj[2*q+1] + fmaf(ea1, wv[2*q+1], b1[2*q+1]));
          a0.u[q] = pack_tr(v00, v01);
          a1.u[q] = pack_tr(v10, v11);
        }
        f32x4 d00 = __builtin_amdgcn_mfma_f32_16x16x32_bf16(a0.v, bf0, zero, 0, 0, 0);
        f32x4 d01 = __builtin_amdgcn_mfma_f32_16x16x32_bf16(a0.v, bf1, zero, 0, 0, 0);
        f32x4 d10 = __builtin_amdgcn_mfma_f32_16x16x32_bf16(a1.v, bf0, zero, 0, 0, 0);
        f32x4 d11 = __builtin_amdgcn_mfma_f32_16x16x32_bf16(a1.v, bf1, zero, 0, 0, 0);
        #pragma unroll
        for (int nt = 0; nt < 2; ++nt) {
          f32x4 da = nt ? d01 : d00;
          f32x4 db = nt ? d11 : d10;
          // max over raw values first; lrelu is monotone -> apply once at the end
          float mv = fmaxf(fmaxf(fmaxf(da[0], da[1]), fmaxf(da[2], da[3])),
                           fmaxf(fmaxf(db[0], db[1]), fmaxf(db[2], db[3])));
          mv = fmaxf(mv, __shfl_xor(mv, 16));
          mv = fmaxf(mv, __shfl_xor(mv, 32));
          if (lane < 16) saggr[j * S4 + nt * 16 + lane] = lrelu(mv);
        }
      }
    }

    // u = lrelu([enc | aggr] @ W_u.T) -> sA (own rows)
    {
      const f32x2* e2 = (const f32x2*)&senc[p * S4];
      const f32x2* g2 = (const f32x2*)&saggr[p * S4];
      f32x2 acc2 = {0.f, 0.f};
      #pragma unroll
      for (int c2 = 0; c2 < 16; ++c2)
        acc2 = __builtin_elementwise_fma(sWu2[k * 33 + c2], e2[c2], acc2);
      #pragma unroll
      for (int c2 = 0; c2 < 16; ++c2)
        acc2 = __builtin_elementwise_fma(sWu2[k * 33 + 16 + c2], g2[c2], acc2);
      float ur = acc2.x + acc2.y;
      sA[p * S4 + k] = lrelu(ur);
    }

    // GRU (own rows)
    float hnew;
    {
      const f32x2* u2 = (const f32x2*)&sA[p * S4];
      const f32x2* h2 = (const f32x2*)&sh[p * S4];
      f32x2 gr = {0,0}, gz = {0,0}, gn = {0,0}, hr = {0,0}, hz = {0,0}, hn = {0,0};
      #pragma unroll
      for (int c2 = 0; c2 < 16; ++c2) {
        f32x2 uu = u2[c2], hh = h2[c2];
        gr = __builtin_elementwise_fma(bf2f2(sWih2[k * 17 + c2]),        uu, gr);
        gz = __builtin_elementwise_fma(bf2f2(sWih2[(32 + k) * 17 + c2]), uu, gz);
        gn = __builtin_elementwise_fma(bf2f2(sWih2[(64 + k) * 17 + c2]), uu, gn);
        hr = __builtin_elementwise_fma(bf2f2(sWhh2[k * 17 + c2]),        hh, hr);
        hz = __builtin_elementwise_fma(bf2f2(sWhh2[(32 + k) * 17 + c2]), hh, hz);
        hn = __builtin_elementwise_fma(bf2f2(sWhh2[(64 + k) * 17 + c2]), hh, hn);
      }
      float r  = fsigmoid((gr.x + gr.y) + (hr.x + hr.y));
      float z  = fsigmoid((gz.x + gz.y) + (hz.x + hz.y));
      float nn = ftanh((gn.x + gn.y) + r * (hn.x + hn.y));
      hnew = (1.f - z) * nn + z * sh[p * S4 + k];
    }
    sh[p * S4 + k] = hnew;

    // mst partial, reduce over feature lanes (all waves, own rows)
    {
      float part = sWmst[k] * senc[p * S4 + k] + sWmst[32 + k] * sh[p * S4 + k];
      #pragma unroll
      for (int mask = 1; mask <= 16; mask <<= 1) part += __shfl_xor(part, mask);
      if (k == 0) smst[p] = part;
    }
    lds_barrier();   // B2: smst all rows visible

    // masked argmax + prev update — EVERY wave computes redundantly (same result),
    // so its own sprev write is visible to its own next-step reads (no 3rd barrier)
    {
      float val = (sprev[l32] > 0.f) ? NEGV : smst[l32];
      int idx = l32;
      #pragma unroll
      for (int mask = 16; mask >= 1; mask >>= 1) {
        float ov = __shfl_xor(val, mask);
        int   oi = __shfl_xor(idx, mask);
        if (ov > val || (ov == val && oi < idx)) { val = ov; idx = oi; }
      }
      if (l32 == idx) sprev[l32] = 1.0f;   // all waves write same value: benign
    }
  }

  // ---- final predictor ----
  {
    float c1 = 0.f, c2 = 0.f;
    #pragma unroll
    for (int c = 0; c < 32; ++c) {
      float hc = sh[p * S4 + c];
      c1 = fmaf(W_p1[k * 65 + c],      hc, c1);
      c2 = fmaf(W_p1[k * 65 + 32 + c], hc, c2);
    }
    sA[p * S4 + k] = c1;
    sB[p * S3 + k] = c2;
  }
  if (t < 32) swea[t] = W_p1[t * 65 + 64];
  lds_barrier();

  // out(src=i, dst=j): i = p, j = k
  {
    const int i = p, j = k;
    float eat = sea[j * S3 + i];
    float acc = 0.f;
    #pragma unroll
    for (int c = 0; c < 32; ++c) {
      float v = sA[i * S4 + c] + sB[j * S3 + c] + eat * swea[c];
      acc = fmaf(W_p2[c], fmaxf(v, 0.f), acc);
    }
    out[(size_t)(g * NL + i) * NTOT + (g * NL + j)] = acc;
  }
}

extern "C" void kernel_launch(void* const* d_in, const int* in_sizes, int n_in,
                              void* d_out, int out_size, void* d_ws, size_t ws_size,
                              hipStream_t stream) {
  const float* x         = (const float*)d_in[0];
  const float* edge_attr = (const float*)d_in[1];
  const float* W_enc     = (const float*)d_in[2];
  const float* W_m1      = (const float*)d_in[3];
  const float* W_m2      = (const float*)d_in[4];
  const float* W_u       = (const float*)d_in[5];
  const float* W_ih      = (const float*)d_in[6];
  const float* W_hh      = (const float*)d_in[7];
  const float* W_mst     = (const float*)d_in[8];
  const float* W_p1      = (const float*)d_in[9];
  const float* W_p2      = (const float*)d_in[10];
  float* out = (float*)d_out;

  hipLaunchKernelGGL(prims_fused, dim3(NG), dim3(NT), 0, stream,
                     x, edge_attr, W_enc, W_m1, W_m2, W_u, W_ih, W_hh,
                     W_mst, W_p1, W_p2, out);
}